// Round 1
// 4198.892 us; speedup vs baseline: 1.7829x; 1.7829x over previous
//
#include <hip/hip_runtime.h>

// Problem constants
#define VV 10000
#define DD 512
#define HH 8
#define DH 64
#define DI 2048
#define LL 12
#define BB 4
#define SS 1024
#define TT (BB * SS)   // 4096 tokens

// fp32 inputs/outputs confirmed. GEMMs now run on matrix cores via
// split-bf16: x = hi + lo (both bf16), A*B ~= Ah*Bh + Ah*Bl + Al*Bh,
// fp32 accumulation in MFMA. Dropped lo*lo term ~2^-18 relative.

typedef __attribute__((ext_vector_type(8))) short bhalf8;    // 8 bf16 = 4 VGPRs
typedef __attribute__((ext_vector_type(16))) float f32x16;   // MFMA 32x32 accum

// RNE split of fp32 into bf16 hi + bf16 lo.
__device__ __forceinline__ void split_bf16(float x, unsigned short& h, unsigned short& l)
{
    unsigned int u = __float_as_uint(x);
    unsigned int r = (u + 0x7FFFu + ((u >> 16) & 1u)) & 0xFFFF0000u;
    h = (unsigned short)(r >> 16);
    float lf = x - __uint_as_float(r);          // exact (Sterbenz-range)
    unsigned int ul = __float_as_uint(lf);
    l = (unsigned short)((ul + 0x7FFFu + ((ul >> 16) & 1u)) >> 16);
}

// ---------------------------------------------------------------------------
// fp32 -> (bf16 hi, bf16 lo) bulk converter. n4 = element count / 4.
// ---------------------------------------------------------------------------
__global__ __launch_bounds__(256) void convsplit(
    const float* __restrict__ src, unsigned short* __restrict__ hi,
    unsigned short* __restrict__ lo, int n4)
{
    int stride = gridDim.x * 256;
    for (int i = blockIdx.x * 256 + threadIdx.x; i < n4; i += stride) {
        float4 v = ((const float4*)src)[i];
        ushort4 h, l;
        split_bf16(v.x, h.x, l.x);
        split_bf16(v.y, h.y, l.y);
        split_bf16(v.z, h.z, l.z);
        split_bf16(v.w, h.w, l.w);
        ((ushort4*)hi)[i] = h;
        ((ushort4*)lo)[i] = l;
    }
}

// ---------------------------------------------------------------------------
// Embedding: h = word_emb[data] + pos_emb ; also emits bf16 hi/lo pair.
// ---------------------------------------------------------------------------
__global__ __launch_bounds__(256) void embed_kernel(
    const int* __restrict__ data, const float* __restrict__ we,
    const float* __restrict__ pe, float* __restrict__ h,
    unsigned short* __restrict__ hhi, unsigned short* __restrict__ hlo)
{
    int tok = blockIdx.x;
    int tid = threadIdx.x;
    int idx = data[tok];
    int s = tok & (SS - 1);
    size_t base = (size_t)tok * DD;
    size_t wb = (size_t)idx * DD;
    size_t pb = (size_t)s * DD;
    float a = we[wb + tid] + pe[pb + tid];
    float b = we[wb + 256 + tid] + pe[pb + 256 + tid];
    h[base + tid] = a;
    h[base + 256 + tid] = b;
    unsigned short hx, lx;
    split_bf16(a, hx, lx); hhi[base + tid] = hx;       hlo[base + tid] = lx;
    split_bf16(b, hx, lx); hhi[base + 256 + tid] = hx; hlo[base + 256 + tid] = lx;
}

// ---------------------------------------------------------------------------
// Split-bf16 MFMA GEMM: C[M,N] = A[M,K] * W[N,K]^T (+bias)(+relu)
// A,W given as bf16 hi/lo pairs (row-major, K contiguous). M = 4096.
// Block tile 128 x BN, 4 waves (2x2), wave tile 64 x BN/2,
// fragments 32x32 via v_mfma_f32_32x32x16_bf16 (3 MFMA per fragment pair).
// LDS: k-chunk-major [slot(8)][row][16B] with row^slot swizzle ->
// both ds_write_b128 and ds_read_b128 are bank-uniform (no conflicts).
// EPI: 0 none->fp32 C, 1 +bias->fp32 C, 2 +bias+relu->bf16 pair (Chp/Clp).
// ---------------------------------------------------------------------------
template<int BN, int EPI>
__global__ __launch_bounds__(256) void gemm_mfma(
    const unsigned short* __restrict__ Ahp, const unsigned short* __restrict__ Alp,
    const unsigned short* __restrict__ Whp, const unsigned short* __restrict__ Wlp,
    const float* __restrict__ bias, float* __restrict__ C,
    unsigned short* __restrict__ Chp, unsigned short* __restrict__ Clp,
    int N, int K)
{
    constexpr int FN  = BN / 64;           // n-fragments per wave
    constexpr int BT  = BN * 128;          // bytes per B tile (8 slots * BN * 16)
    constexpr int NBG = BN / 8;            // 8-row staging groups per B tile
    constexpr int NGRP = 32 + 2 * NBG;     // total staging groups per K-step
    constexpr int PW  = NGRP / 4;          // groups per wave
    __shared__ __align__(16) char smem[32768 + 2 * BT];  // Ah|Al|Bh|Bl

    const int tid   = threadIdx.x;
    const int lane  = tid & 63;
    const int wid   = tid >> 6;
    const int wm    = wid >> 1;
    const int wn    = wid & 1;
    const int laneM = lane & 31;
    const int laneK = lane >> 5;
    const int m0    = blockIdx.y * 128;
    const int n0    = blockIdx.x * BN;
    const int srow8 = lane >> 3;           // row-within-group for staging
    const int sslot = lane & 7;            // k-chunk (8 bf16) for staging

    f32x16 acc[2][FN];
    #pragma unroll
    for (int i = 0; i < 2; ++i)
        #pragma unroll
        for (int j = 0; j < FN; ++j)
            #pragma unroll
            for (int r = 0; r < 16; ++r) acc[i][j][r] = 0.f;

    for (int k0 = 0; k0 < K; k0 += 64) {
        __syncthreads();                   // previous tile's reads complete
        bhalf8 rbuf[PW];
        #pragma unroll
        for (int t = 0; t < PW; ++t) {
            int g = wid * PW + t;
            const unsigned short* src;
            if (g < 32) {                  // A tiles: 16 groups hi, 16 lo
                const unsigned short* bp = (g < 16) ? Ahp : Alp;
                int row = (g & 15) * 8 + srow8;
                src = bp + (size_t)(m0 + row) * K + (k0 + sslot * 8);
            } else {                       // B tiles
                int d = g - 32;
                const unsigned short* bp = (d < NBG) ? Whp : Wlp;
                int row = (d & (NBG - 1)) * 8 + srow8;
                int n = n0 + row;
                n = (n < N) ? n : (N - 1); // clamp (logits tail); stores guarded
                src = bp + (size_t)n * K + (k0 + sslot * 8);
            }
            rbuf[t] = *(const bhalf8*)src;
        }
        #pragma unroll
        for (int t = 0; t < PW; ++t) {
            int g = wid * PW + t;
            int off;
            if (g < 32) {
                int row = (g & 15) * 8 + srow8;
                off = ((g >> 4) << 14) + sslot * 2048 + ((row ^ sslot) << 4);
            } else {
                int d = g - 32;
                int row = (d & (NBG - 1)) * 8 + srow8;
                off = 32768 + ((d < NBG) ? 0 : BT)
                    + sslot * (BN * 16) + ((row ^ sslot) << 4);
            }
            *(bhalf8*)(smem + off) = rbuf[t];
        }
        __syncthreads();                   // staging visible

        #pragma unroll
        for (int kb = 0; kb < 4; ++kb) {   // 4 x (k=16) per K-step
            const int slot = kb * 2 + laneK;
            bhalf8 ah[2], al[2], bh[FN], bl[FN];
            #pragma unroll
            for (int i = 0; i < 2; ++i) {
                int row = wm * 64 + i * 32 + laneM;
                int off = slot * 2048 + ((row ^ slot) << 4);
                ah[i] = *(const bhalf8*)(smem + off);
                al[i] = *(const bhalf8*)(smem + 16384 + off);
            }
            #pragma unroll
            for (int j = 0; j < FN; ++j) {
                int row = wn * (BN / 2) + j * 32 + laneM;
                int off = 32768 + slot * (BN * 16) + ((row ^ slot) << 4);
                bh[j] = *(const bhalf8*)(smem + off);
                bl[j] = *(const bhalf8*)(smem + BT + off);
            }
            #pragma unroll
            for (int i = 0; i < 2; ++i)
                #pragma unroll
                for (int j = 0; j < FN; ++j) {
                    acc[i][j] = __builtin_amdgcn_mfma_f32_32x32x16_bf16(ah[i], bh[j], acc[i][j], 0, 0, 0);
                    acc[i][j] = __builtin_amdgcn_mfma_f32_32x32x16_bf16(ah[i], bl[j], acc[i][j], 0, 0, 0);
                    acc[i][j] = __builtin_amdgcn_mfma_f32_32x32x16_bf16(al[i], bh[j], acc[i][j], 0, 0, 0);
                }
        }
    }

    // Epilogue. C/D layout (m74/m101): col = lane&31, row = (r&3)+8*(r>>2)+4*laneK
    #pragma unroll
    for (int j = 0; j < FN; ++j) {
        int ncol = n0 + wn * (BN / 2) + j * 32 + laneM;
        bool nok = (ncol < N);
        float bv = 0.f;
        if (EPI >= 1 && nok) bv = bias[ncol];
        #pragma unroll
        for (int i = 0; i < 2; ++i) {
            #pragma unroll
            for (int r = 0; r < 16; ++r) {
                int mrow = m0 + wm * 64 + i * 32 + (r & 3) + ((r >> 2) << 3) + laneK * 4;
                float v = acc[i][j][r] + bv;
                if (EPI == 2) v = fmaxf(v, 0.f);
                if (nok) {
                    if (EPI == 2) {
                        unsigned short hx, lx;
                        split_bf16(v, hx, lx);
                        Chp[(size_t)mrow * N + ncol] = hx;
                        Clp[(size_t)mrow * N + ncol] = lx;
                    } else {
                        C[(size_t)mrow * N + ncol] = v;
                    }
                }
            }
        }
    }
}

// ---------------------------------------------------------------------------
// Flash-style causal attention (fp32 VALU, unchanged math).
// Epilogue now emits av as bf16 hi/lo pair for the MFMA o-projection.
// ---------------------------------------------------------------------------
__global__ __launch_bounds__(256) void flash_attn(
    const float* __restrict__ q, const float* __restrict__ kv,
    unsigned short* __restrict__ avh, unsigned short* __restrict__ avl)
{
    __shared__ __align__(16) float QsT[64][68];
    __shared__ __align__(16) float KPT[64][68];
    __shared__ __align__(16) float Vs [64][68];

    const int qt = 15 - (int)blockIdx.x;   // heavy q-tiles dispatched first
    const int hh = blockIdx.y;
    const int b  = blockIdx.z;
    const int tid = threadIdx.x;
    const int tx = tid & 15;
    const int ty = tid >> 4;
    const int q0 = qt * 64;

    const int srow = tid >> 2;
    const int sc0  = (tid & 3) * 16;

    {
        const float* src = q + ((size_t)(b * SS + q0 + srow) * 512) + hh * 64 + sc0;
        #pragma unroll
        for (int m = 0; m < 4; ++m) {
            float4 v = *(const float4*)(src + 4 * m);
            QsT[sc0 + 4*m + 0][srow] = v.x * 0.125f;
            QsT[sc0 + 4*m + 1][srow] = v.y * 0.125f;
            QsT[sc0 + 4*m + 2][srow] = v.z * 0.125f;
            QsT[sc0 + 4*m + 3][srow] = v.w * 0.125f;
        }
    }

    float mrun[4], lrun[4], O[4][4];
    #pragma unroll
    for (int ii = 0; ii < 4; ++ii) {
        mrun[ii] = -1e30f; lrun[ii] = 0.f;
        #pragma unroll
        for (int jj = 0; jj < 4; ++jj) O[ii][jj] = 0.f;
    }

    for (int kt = 0; kt <= qt; ++kt) {
        __syncthreads();
        {
            const float* kp = kv + ((size_t)(b * SS + kt * 64 + srow) * 1024) + hh * 64 + sc0;
            #pragma unroll
            for (int m = 0; m < 4; ++m) {
                float4 kk = *(const float4*)(kp + 4 * m);
                KPT[sc0 + 4*m + 0][srow] = kk.x;
                KPT[sc0 + 4*m + 1][srow] = kk.y;
                KPT[sc0 + 4*m + 2][srow] = kk.z;
                KPT[sc0 + 4*m + 3][srow] = kk.w;
                *(float4*)&Vs[srow][sc0 + 4*m] = *(const float4*)(kp + 512 + 4 * m);
            }
        }
        __syncthreads();

        float S[4][4] = {};
        #pragma unroll 8
        for (int d = 0; d < 64; ++d) {
            float4 qv = *(const float4*)&QsT[d][ty * 4];
            float4 kk = *(const float4*)&KPT[d][tx * 4];
            float qa[4] = {qv.x, qv.y, qv.z, qv.w};
            float ka[4] = {kk.x, kk.y, kk.z, kk.w};
            #pragma unroll
            for (int ii = 0; ii < 4; ++ii)
                #pragma unroll
                for (int jj = 0; jj < 4; ++jj)
                    S[ii][jj] += qa[ii] * ka[jj];
        }

        if (kt == qt) {
            #pragma unroll
            for (int ii = 0; ii < 4; ++ii)
                #pragma unroll
                for (int jj = 0; jj < 4; ++jj)
                    if (tx * 4 + jj > ty * 4 + ii) S[ii][jj] = -1e30f;
        }

        #pragma unroll
        for (int ii = 0; ii < 4; ++ii) {
            float mx = fmaxf(fmaxf(S[ii][0], S[ii][1]), fmaxf(S[ii][2], S[ii][3]));
            mx = fmaxf(mx, __shfl_xor(mx, 1));
            mx = fmaxf(mx, __shfl_xor(mx, 2));
            mx = fmaxf(mx, __shfl_xor(mx, 4));
            mx = fmaxf(mx, __shfl_xor(mx, 8));
            float mn = fmaxf(mrun[ii], mx);
            float alpha = __expf(mrun[ii] - mn);
            mrun[ii] = mn;
            float rs = 0.f;
            #pragma unroll
            for (int jj = 0; jj < 4; ++jj) {
                float p = __expf(S[ii][jj] - mn);
                S[ii][jj] = p;
                rs += p;
            }
            rs += __shfl_xor(rs, 1);
            rs += __shfl_xor(rs, 2);
            rs += __shfl_xor(rs, 4);
            rs += __shfl_xor(rs, 8);
            lrun[ii] = lrun[ii] * alpha + rs;
            #pragma unroll
            for (int jj = 0; jj < 4; ++jj) O[ii][jj] *= alpha;
        }

        __syncthreads();
        #pragma unroll
        for (int jj = 0; jj < 4; ++jj) {
            float4 p4 = make_float4(S[0][jj], S[1][jj], S[2][jj], S[3][jj]);
            *(float4*)&KPT[tx * 4 + jj][ty * 4] = p4;
        }
        __syncthreads();

        #pragma unroll 8
        for (int k = 0; k < 64; ++k) {
            float4 p4 = *(const float4*)&KPT[k][ty * 4];
            float4 v4 = *(const float4*)&Vs[k][tx * 4];
            float pa[4] = {p4.x, p4.y, p4.z, p4.w};
            float va[4] = {v4.x, v4.y, v4.z, v4.w};
            #pragma unroll
            for (int ii = 0; ii < 4; ++ii)
                #pragma unroll
                for (int jj = 0; jj < 4; ++jj)
                    O[ii][jj] += pa[ii] * va[jj];
        }
    }

    #pragma unroll
    for (int ii = 0; ii < 4; ++ii) {
        float inv = 1.0f / lrun[ii];
        ushort4 hv, lv;
        split_bf16(O[ii][0] * inv, hv.x, lv.x);
        split_bf16(O[ii][1] * inv, hv.y, lv.y);
        split_bf16(O[ii][2] * inv, hv.z, lv.z);
        split_bf16(O[ii][3] * inv, hv.w, lv.w);
        size_t base = ((size_t)(b * SS + q0 + ty * 4 + ii) * 512) + hh * 64 + tx * 4;
        *(ushort4*)(avh + base) = hv;
        *(ushort4*)(avl + base) = lv;
    }
}

// ---------------------------------------------------------------------------
// Fused residual-add + LayerNorm; also emits bf16 hi/lo pair of the output.
// ---------------------------------------------------------------------------
__global__ __launch_bounds__(256) void add_ln_kernel(
    float* __restrict__ h, const float* __restrict__ x,
    const float* __restrict__ g, const float* __restrict__ bta,
    unsigned short* __restrict__ hhi, unsigned short* __restrict__ hlo)
{
    int tok = blockIdx.x, tid = threadIdx.x;
    size_t base = (size_t)tok * DD;
    float v0 = h[base + tid] + x[base + tid];
    float v1 = h[base + 256 + tid] + x[base + 256 + tid];

    __shared__ float rs[256], rq[256];
    rs[tid] = v0 + v1;
    rq[tid] = v0 * v0 + v1 * v1;
    __syncthreads();
    for (int off = 128; off > 0; off >>= 1) {
        if (tid < off) { rs[tid] += rs[tid + off]; rq[tid] += rq[tid + off]; }
        __syncthreads();
    }
    float mean = rs[0] * (1.f / 512.f);
    float var  = rq[0] * (1.f / 512.f) - mean * mean;
    float inv  = rsqrtf(var + 1e-5f);
    float o0 = (v0 - mean) * inv * g[tid]       + bta[tid];
    float o1 = (v1 - mean) * inv * g[256 + tid] + bta[256 + tid];
    h[base + tid]       = o0;
    h[base + 256 + tid] = o1;
    unsigned short a, b;
    split_bf16(o0, a, b); hhi[base + tid]       = a; hlo[base + tid]       = b;
    split_bf16(o1, a, b); hhi[base + 256 + tid] = a; hlo[base + 256 + tid] = b;
}

// ---------------------------------------------------------------------------
extern "C" void kernel_launch(void* const* d_in, const int* in_sizes, int n_in,
                              void* d_out, int out_size, void* d_ws, size_t ws_size,
                              hipStream_t stream)
{
    const int*   data = (const int*)d_in[0];
    const float* we   = (const float*)d_in[1];   // word_emb [V, D]
    const float* pe   = (const float*)d_in[2];   // pos_emb
    const float* Wq   = (const float*)d_in[3];   // [L, 512, 512]
    const float* Wkv  = (const float*)d_in[4];   // [L, 1024, 512]
    const float* Wo   = (const float*)d_in[5];   // [L, 512, 512]
    const float* g1   = (const float*)d_in[6];
    const float* bl1  = (const float*)d_in[7];
    const float* W1   = (const float*)d_in[8];   // [L, 2048, 512]
    const float* b1   = (const float*)d_in[9];
    const float* W2   = (const float*)d_in[10];  // [L, 512, 2048]
    const float* b2   = (const float*)d_in[11];
    const float* g2   = (const float*)d_in[12];
    const float* bl2  = (const float*)d_in[13];
    const float* outb = (const float*)d_in[14];  // [V]
    float* out = (float*)d_out;

    // Workspace layout (~221 MB total)
    float* h   = (float*)d_ws;                                   // 8 MB
    float* q   = h  + (size_t)TT * 512;                          // 8 MB
    float* kv  = q  + (size_t)TT * 512;                          // 16 MB
    unsigned short* avh = (unsigned short*)(kv + (size_t)TT * 1024);  // 4 MB
    unsigned short* avl = avh + (size_t)TT * 512;                     // 4 MB
    float* tmp = (float*)(avl + (size_t)TT * 512);               // 8 MB
    unsigned short* hhi = (unsigned short*)(tmp + (size_t)TT * 512);  // 4 MB
    unsigned short* hlo = hhi + (size_t)TT * 512;                     // 4 MB
    // ff pair aliases [q .. av_l) = exactly 32 MB; q/kv/av dead when ff live
    unsigned short* ffh = (unsigned short*)q;
    unsigned short* ffl = ffh + (size_t)TT * 2048;
    // pre-converted weights (bf16 hi/lo)
    unsigned short* wqh  = hlo + (size_t)TT * 512;
    unsigned short* wql  = wqh  + (size_t)LL * 512 * 512;
    unsigned short* wkvh = wql  + (size_t)LL * 512 * 512;
    unsigned short* wkvl = wkvh + (size_t)LL * 1024 * 512;
    unsigned short* woh  = wkvl + (size_t)LL * 1024 * 512;
    unsigned short* wol  = woh  + (size_t)LL * 512 * 512;
    unsigned short* w1h  = wol  + (size_t)LL * 512 * 512;
    unsigned short* w1l  = w1h  + (size_t)LL * 2048 * 512;
    unsigned short* w2h  = w1l  + (size_t)LL * 2048 * 512;
    unsigned short* w2l  = w2h  + (size_t)LL * 512 * 2048;
    unsigned short* weh  = w2l  + (size_t)LL * 512 * 2048;
    unsigned short* wel  = weh  + (size_t)VV * 512;

    auto cv = [&](const float* s, unsigned short* hh, unsigned short* ll, size_t n) {
        int n4 = (int)(n >> 2);
        int blocks = (n4 + 255) / 256;
        if (blocks > 2048) blocks = 2048;
        convsplit<<<blocks, 256, 0, stream>>>(s, hh, ll, n4);
    };
    cv(Wq,  wqh,  wql,  (size_t)LL * 512 * 512);
    cv(Wkv, wkvh, wkvl, (size_t)LL * 1024 * 512);
    cv(Wo,  woh,  wol,  (size_t)LL * 512 * 512);
    cv(W1,  w1h,  w1l,  (size_t)LL * 2048 * 512);
    cv(W2,  w2h,  w2l,  (size_t)LL * 512 * 2048);
    cv(we,  weh,  wel,  (size_t)VV * 512);

    embed_kernel<<<TT, 256, 0, stream>>>(data, we, pe, h, hhi, hlo);

    for (int l = 0; l < LL; ++l) {
        const unsigned short* lwqh  = wqh  + (size_t)l * 512 * 512;
        const unsigned short* lwql  = wql  + (size_t)l * 512 * 512;
        const unsigned short* lwkvh = wkvh + (size_t)l * 1024 * 512;
        const unsigned short* lwkvl = wkvl + (size_t)l * 1024 * 512;
        const unsigned short* lwoh  = woh  + (size_t)l * 512 * 512;
        const unsigned short* lwol  = wol  + (size_t)l * 512 * 512;
        const unsigned short* lw1h  = w1h  + (size_t)l * 2048 * 512;
        const unsigned short* lw1l  = w1l  + (size_t)l * 2048 * 512;
        const unsigned short* lw2h  = w2h  + (size_t)l * 512 * 2048;
        const unsigned short* lw2l  = w2l  + (size_t)l * 512 * 2048;

        gemm_mfma<64, 0><<<dim3(8, 32), 256, 0, stream>>>(
            hhi, hlo, lwqh, lwql, nullptr, q, nullptr, nullptr, 512, 512);
        gemm_mfma<128, 0><<<dim3(8, 32), 256, 0, stream>>>(
            hhi, hlo, lwkvh, lwkvl, nullptr, kv, nullptr, nullptr, 1024, 512);
        flash_attn<<<dim3(16, HH, BB), 256, 0, stream>>>(q, kv, avh, avl);
        gemm_mfma<64, 0><<<dim3(8, 32), 256, 0, stream>>>(
            avh, avl, lwoh, lwol, nullptr, tmp, nullptr, nullptr, 512, 512);
        add_ln_kernel<<<TT, 256, 0, stream>>>(h, tmp, g1 + l * 512, bl1 + l * 512, hhi, hlo);
        gemm_mfma<128, 2><<<dim3(16, 32), 256, 0, stream>>>(
            hhi, hlo, lw1h, lw1l, b1 + l * 2048, nullptr, ffh, ffl, 2048, 512);
        gemm_mfma<64, 1><<<dim3(8, 32), 256, 0, stream>>>(
            ffh, ffl, lw2h, lw2l, b2 + l * 512, tmp, nullptr, nullptr, 512, 2048);
        add_ln_kernel<<<TT, 256, 0, stream>>>(h, tmp, g2 + l * 512, bl2 + l * 512, hhi, hlo);
    }

    // logits = h @ word_emb^T + out_b (tied), N = 10000
    gemm_mfma<128, 1><<<dim3((VV + 127) / 128, 32), 256, 0, stream>>>(
        hhi, hlo, weh, wel, outb, out, nullptr, nullptr, VV, 512);
}

// Round 2
// 3499.963 us; speedup vs baseline: 2.1389x; 1.1997x over previous
//
#include <hip/hip_runtime.h>

// Problem constants
#define VV 10000
#define DD 512
#define HH 8
#define DH 64
#define DI 2048
#define LL 12
#define BB 4
#define SS 1024
#define TT (BB * SS)   // 4096 tokens

// All GEMMs and attention on matrix cores via split-bf16:
// x = hi + lo (both bf16), A*B ~= Ah*Bh + Ah*Bl + Al*Bh, fp32 MFMA accum.

typedef __attribute__((ext_vector_type(8))) short bhalf8;    // 8 bf16 = 4 VGPRs
typedef __attribute__((ext_vector_type(16))) float f32x16;   // MFMA 32x32 accum

// RNE split of fp32 into bf16 hi + bf16 lo.
__device__ __forceinline__ void split_bf16(float x, unsigned short& h, unsigned short& l)
{
    unsigned int u = __float_as_uint(x);
    unsigned int r = (u + 0x7FFFu + ((u >> 16) & 1u)) & 0xFFFF0000u;
    h = (unsigned short)(r >> 16);
    float lf = x - __uint_as_float(r);          // exact (Sterbenz-range)
    unsigned int ul = __float_as_uint(lf);
    l = (unsigned short)((ul + 0x7FFFu + ((ul >> 16) & 1u)) >> 16);
}

// ---------------------------------------------------------------------------
// fp32 -> (bf16 hi, bf16 lo) bulk converter. n4 = element count / 4.
// ---------------------------------------------------------------------------
__global__ __launch_bounds__(256) void convsplit(
    const float* __restrict__ src, unsigned short* __restrict__ hi,
    unsigned short* __restrict__ lo, int n4)
{
    int stride = gridDim.x * 256;
    for (int i = blockIdx.x * 256 + threadIdx.x; i < n4; i += stride) {
        float4 v = ((const float4*)src)[i];
        ushort4 h, l;
        split_bf16(v.x, h.x, l.x);
        split_bf16(v.y, h.y, l.y);
        split_bf16(v.z, h.z, l.z);
        split_bf16(v.w, h.w, l.w);
        ((ushort4*)hi)[i] = h;
        ((ushort4*)lo)[i] = l;
    }
}

// ---------------------------------------------------------------------------
// Embedding: h = word_emb[data] + pos_emb ; also emits bf16 hi/lo pair.
// ---------------------------------------------------------------------------
__global__ __launch_bounds__(256) void embed_kernel(
    const int* __restrict__ data, const float* __restrict__ we,
    const float* __restrict__ pe, float* __restrict__ h,
    unsigned short* __restrict__ hhi, unsigned short* __restrict__ hlo)
{
    int tok = blockIdx.x;
    int tid = threadIdx.x;
    int idx = data[tok];
    int s = tok & (SS - 1);
    size_t base = (size_t)tok * DD;
    size_t wb = (size_t)idx * DD;
    size_t pb = (size_t)s * DD;
    float a = we[wb + tid] + pe[pb + tid];
    float b = we[wb + 256 + tid] + pe[pb + 256 + tid];
    h[base + tid] = a;
    h[base + 256 + tid] = b;
    unsigned short hx, lx;
    split_bf16(a, hx, lx); hhi[base + tid] = hx;       hlo[base + tid] = lx;
    split_bf16(b, hx, lx); hhi[base + 256 + tid] = hx; hlo[base + 256 + tid] = lx;
}

// ---------------------------------------------------------------------------
// Split-bf16 MFMA GEMM: C[M,N] = A[M,K] * W[N,K]^T (+bias)(+relu)
// Block tile 128 x BN, 4 waves (2x2), wave tile 64 x BN/2,
// fragments 32x32 via v_mfma_f32_32x32x16_bf16 (3 MFMA per fragment pair).
// LDS: k-chunk-major [slot(8)][row][16B] with row^slot swizzle.
// EPI: 0 fp32, 1 fp32+bias, 2 bias+relu->pair, 3 pair,
//      4 kv: n<512 -> K pair [m][512]; n>=512 -> Vt pair [(n-512)*TT + m].
// SWZ: bijective XCD-aware block remap (use for the big logits GEMM).
// ---------------------------------------------------------------------------
template<int BN, int EPI, bool SWZ>
__global__ __launch_bounds__(256) void gemm_mfma(
    const unsigned short* __restrict__ Ahp, const unsigned short* __restrict__ Alp,
    const unsigned short* __restrict__ Whp, const unsigned short* __restrict__ Wlp,
    const float* __restrict__ bias, float* __restrict__ C,
    unsigned short* __restrict__ Chp, unsigned short* __restrict__ Clp,
    unsigned short* __restrict__ Vhp, unsigned short* __restrict__ Vlp,
    int N, int K)
{
    constexpr int FN  = BN / 64;           // n-fragments per wave
    constexpr int BT  = BN * 128;          // bytes per B tile (8 slots * BN * 16)
    constexpr int NBG = BN / 8;            // 8-row staging groups per B tile
    constexpr int NGRP = 32 + 2 * NBG;     // total staging groups per K-step
    constexpr int PW  = NGRP / 4;          // groups per wave
    __shared__ __align__(16) char smem[32768 + 2 * BT];  // Ah|Al|Bh|Bl

    int bx = blockIdx.x, by = blockIdx.y;
    if (SWZ) {
        int nwg = gridDim.x * gridDim.y;
        int id = by * gridDim.x + bx;
        int nq = nwg >> 3, rr = nwg & 7;
        int xcd = id & 7, j = id >> 3;
        int nid = (xcd < rr) ? (xcd * (nq + 1) + j)
                             : (rr * (nq + 1) + (xcd - rr) * nq + j);
        bx = nid % gridDim.x;
        by = nid / gridDim.x;
    }

    const int tid   = threadIdx.x;
    const int lane  = tid & 63;
    const int wid   = tid >> 6;
    const int wm    = wid >> 1;
    const int wn    = wid & 1;
    const int laneM = lane & 31;
    const int laneK = lane >> 5;
    const int m0    = by * 128;
    const int n0    = bx * BN;
    const int srow8 = lane >> 3;           // row-within-group for staging
    const int sslot = lane & 7;            // k-chunk (8 bf16) for staging

    f32x16 acc[2][FN];
    #pragma unroll
    for (int i = 0; i < 2; ++i)
        #pragma unroll
        for (int j = 0; j < FN; ++j)
            #pragma unroll
            for (int r = 0; r < 16; ++r) acc[i][j][r] = 0.f;

    for (int k0 = 0; k0 < K; k0 += 64) {
        __syncthreads();                   // previous tile's reads complete
        bhalf8 rbuf[PW];
        #pragma unroll
        for (int t = 0; t < PW; ++t) {
            int g = wid * PW + t;
            const unsigned short* src;
            if (g < 32) {                  // A tiles: 16 groups hi, 16 lo
                const unsigned short* bp = (g < 16) ? Ahp : Alp;
                int row = (g & 15) * 8 + srow8;
                src = bp + (size_t)(m0 + row) * K + (k0 + sslot * 8);
            } else {                       // B tiles
                int d = g - 32;
                const unsigned short* bp = (d < NBG) ? Whp : Wlp;
                int row = (d & (NBG - 1)) * 8 + srow8;
                int n = n0 + row;
                n = (n < N) ? n : (N - 1); // clamp (logits tail); stores guarded
                src = bp + (size_t)n * K + (k0 + sslot * 8);
            }
            rbuf[t] = *(const bhalf8*)src;
        }
        #pragma unroll
        for (int t = 0; t < PW; ++t) {
            int g = wid * PW + t;
            int off;
            if (g < 32) {
                int row = (g & 15) * 8 + srow8;
                off = ((g >> 4) << 14) + sslot * 2048 + ((row ^ sslot) << 4);
            } else {
                int d = g - 32;
                int row = (d & (NBG - 1)) * 8 + srow8;
                off = 32768 + ((d < NBG) ? 0 : BT)
                    + sslot * (BN * 16) + ((row ^ sslot) << 4);
            }
            *(bhalf8*)(smem + off) = rbuf[t];
        }
        __syncthreads();                   // staging visible

        #pragma unroll
        for (int kb = 0; kb < 4; ++kb) {   // 4 x (k=16) per K-step
            const int slot = kb * 2 + laneK;
            bhalf8 ah[2], al[2], bh[FN], bl[FN];
            #pragma unroll
            for (int i = 0; i < 2; ++i) {
                int row = wm * 64 + i * 32 + laneM;
                int off = slot * 2048 + ((row ^ slot) << 4);
                ah[i] = *(const bhalf8*)(smem + off);
                al[i] = *(const bhalf8*)(smem + 16384 + off);
            }
            #pragma unroll
            for (int j = 0; j < FN; ++j) {
                int row = wn * (BN / 2) + j * 32 + laneM;
                int off = 32768 + slot * (BN * 16) + ((row ^ slot) << 4);
                bh[j] = *(const bhalf8*)(smem + off);
                bl[j] = *(const bhalf8*)(smem + BT + off);
            }
            #pragma unroll
            for (int i = 0; i < 2; ++i)
                #pragma unroll
                for (int j = 0; j < FN; ++j) {
                    acc[i][j] = __builtin_amdgcn_mfma_f32_32x32x16_bf16(ah[i], bh[j], acc[i][j], 0, 0, 0);
                    acc[i][j] = __builtin_amdgcn_mfma_f32_32x32x16_bf16(ah[i], bl[j], acc[i][j], 0, 0, 0);
                    acc[i][j] = __builtin_amdgcn_mfma_f32_32x32x16_bf16(al[i], bh[j], acc[i][j], 0, 0, 0);
                }
        }
    }

    // Epilogue. C/D layout: col = lane&31, row = (r&3)+8*(r>>2)+4*laneK
    #pragma unroll
    for (int j = 0; j < FN; ++j) {
        int ncol = n0 + wn * (BN / 2) + j * 32 + laneM;
        bool nok = (ncol < N);
        float bv = 0.f;
        if (EPI == 1 || EPI == 2) { if (nok) bv = bias[ncol]; }
        #pragma unroll
        for (int i = 0; i < 2; ++i) {
            #pragma unroll
            for (int r = 0; r < 16; ++r) {
                int mrow = m0 + wm * 64 + i * 32 + (r & 3) + ((r >> 2) << 3) + laneK * 4;
                float v = acc[i][j][r] + bv;
                if (EPI == 2) v = fmaxf(v, 0.f);
                if (nok) {
                    if (EPI == 2 || EPI == 3) {
                        unsigned short hx, lx;
                        split_bf16(v, hx, lx);
                        Chp[(size_t)mrow * N + ncol] = hx;
                        Clp[(size_t)mrow * N + ncol] = lx;
                    } else if (EPI == 4) {
                        unsigned short hx, lx;
                        split_bf16(v, hx, lx);
                        if (ncol < 512) {
                            Chp[(size_t)mrow * 512 + ncol] = hx;
                            Clp[(size_t)mrow * 512 + ncol] = lx;
                        } else {
                            Vhp[(size_t)(ncol - 512) * TT + mrow] = hx;
                            Vlp[(size_t)(ncol - 512) * TT + mrow] = lx;
                        }
                    } else {
                        C[(size_t)mrow * N + ncol] = v;
                    }
                }
            }
        }
    }
}

// ---------------------------------------------------------------------------
// MFMA flash attention (split-bf16, causal). One block = 64 q-rows x (head,b),
// 128 threads = 2 waves; wave wq owns q-rows [32*wq, 32*wq+32).
// Swapped QK^T: s = mfma(K, Q) -> C[key][q], col = q = lane&31 -> each lane
// holds 32 keys of ONE q-row; softmax stats are per-lane scalars + one
// shfl_xor(32). P transposed via per-wave LDS, RTZ-split, PV = mfma(Vt, P).
// LDS: K hi/lo + Vt hi/lo (XOR-swizzled, conflict-free b128) + P per wave.
// ---------------------------------------------------------------------------
__global__ __launch_bounds__(128) void flash_mfma(
    const unsigned short* __restrict__ qhp, const unsigned short* __restrict__ qlp,
    const unsigned short* __restrict__ khp, const unsigned short* __restrict__ klp,
    const unsigned short* __restrict__ vthp, const unsigned short* __restrict__ vtlp,
    unsigned short* __restrict__ avh, unsigned short* __restrict__ avl)
{
    __shared__ __align__(16) char lds[50176];   // K 16K | Vt 16K | P 2x8704

    const int qt  = 15 - (int)blockIdx.x;       // heavy q-tiles first
    const int hh  = blockIdx.y;
    const int b   = blockIdx.z;
    const int tid = threadIdx.x;
    const int lane  = tid & 63;
    const int wq    = tid >> 6;
    const int laneM = lane & 31;
    const int laneK = lane >> 5;
    const int q0    = qt * 64;

    // Q fragments (B-operand): col q = laneM, k(d) = 16*ks + 8*laneK + i
    bhalf8 Qh[4], Ql[4];
    {
        size_t qoff = (size_t)(b * SS + q0 + 32 * wq + laneM) * 512 + hh * 64 + 8 * laneK;
        #pragma unroll
        for (int ks = 0; ks < 4; ++ks) {
            Qh[ks] = *(const bhalf8*)(qhp + qoff + 16 * ks);
            Ql[ks] = *(const bhalf8*)(qlp + qoff + 16 * ks);
        }
    }

    f32x16 O0, O1;                              // O^T frags: d-blocks 0,1
    #pragma unroll
    for (int r = 0; r < 16; ++r) { O0[r] = 0.f; O1[r] = 0.f; }
    float mrun = -1e30f, lrun = 0.f;            // per-lane (q = laneM)

    const int srow  = tid >> 1;                 // 0..63 staging row
    const int shalf = tid & 1;                  // 32-elem half
    float* Pl = (float*)(lds + 32768 + wq * 8704);   // [32 q][68]

    for (int kt = 0; kt <= qt; ++kt) {
        __syncthreads();                        // prev-tile LDS reads done
        {
            size_t kbase = (size_t)(b * SS + kt * 64 + srow) * 512 + hh * 64 + 32 * shalf;
            size_t vbase = (size_t)(hh * 64 + srow) * TT + b * SS + kt * 64 + 32 * shalf;
            bhalf8 k0[4], k1[4], v0[4], v1[4];
            #pragma unroll
            for (int j = 0; j < 4; ++j) {
                k0[j] = *(const bhalf8*)(khp  + kbase + 8 * j);
                k1[j] = *(const bhalf8*)(klp  + kbase + 8 * j);
                v0[j] = *(const bhalf8*)(vthp + vbase + 8 * j);
                v1[j] = *(const bhalf8*)(vtlp + vbase + 8 * j);
            }
            int ob = srow * 128 + 64 * shalf;
            int sw = (srow & 7) << 4;
            #pragma unroll
            for (int j = 0; j < 4; ++j) {
                int o = (ob + 16 * j) ^ sw;
                *(bhalf8*)(lds + o)         = k0[j];
                *(bhalf8*)(lds + 8192 + o)  = k1[j];
                *(bhalf8*)(lds + 16384 + o) = v0[j];
                *(bhalf8*)(lds + 24576 + o) = v1[j];
            }
        }
        __syncthreads();                        // tiles staged

        // S^T = K Q^T  (frag s0: keys 0-31, s1: keys 32-63; col = q)
        f32x16 s0, s1;
        #pragma unroll
        for (int r = 0; r < 16; ++r) { s0[r] = 0.f; s1[r] = 0.f; }
        #pragma unroll
        for (int ks = 0; ks < 4; ++ks) {
            int db = 32 * ks + 16 * laneK;
            int o0 = (laneM * 128 + db) ^ ((laneM & 7) << 4);
            int r1 = 32 + laneM;
            int o1 = (r1 * 128 + db) ^ ((r1 & 7) << 4);
            bhalf8 kh0 = *(const bhalf8*)(lds + o0);
            bhalf8 kl0 = *(const bhalf8*)(lds + 8192 + o0);
            bhalf8 kh1 = *(const bhalf8*)(lds + o1);
            bhalf8 kl1 = *(const bhalf8*)(lds + 8192 + o1);
            s0 = __builtin_amdgcn_mfma_f32_32x32x16_bf16(kh0, Qh[ks], s0, 0, 0, 0);
            s0 = __builtin_amdgcn_mfma_f32_32x32x16_bf16(kh0, Ql[ks], s0, 0, 0, 0);
            s0 = __builtin_amdgcn_mfma_f32_32x32x16_bf16(kl0, Qh[ks], s0, 0, 0, 0);
            s1 = __builtin_amdgcn_mfma_f32_32x32x16_bf16(kh1, Qh[ks], s1, 0, 0, 0);
            s1 = __builtin_amdgcn_mfma_f32_32x32x16_bf16(kh1, Ql[ks], s1, 0, 0, 0);
            s1 = __builtin_amdgcn_mfma_f32_32x32x16_bf16(kl1, Qh[ks], s1, 0, 0, 0);
        }

        #pragma unroll
        for (int r = 0; r < 16; ++r) { s0[r] *= 0.125f; s1[r] *= 0.125f; }

        if (kt == qt) {                         // causal mask on diagonal tile
            int qrel = 32 * wq + laneM;
            #pragma unroll
            for (int r = 0; r < 16; ++r) {
                int krel = (r & 3) + ((r >> 2) << 3) + 4 * laneK;
                if (krel > qrel)      s0[r] = -1e30f;
                if (krel + 32 > qrel) s1[r] = -1e30f;
            }
        }

        // online softmax, per-lane scalars (lane = one q-row, 32 of 64 keys;
        // partner lane^32 holds the other 32)
        float mx = s0[0];
        #pragma unroll
        for (int r = 1; r < 16; ++r) mx = fmaxf(mx, s0[r]);
        #pragma unroll
        for (int r = 0; r < 16; ++r) mx = fmaxf(mx, s1[r]);
        mx = fmaxf(mx, __shfl_xor(mx, 32));
        float mn = fmaxf(mrun, mx);
        float alpha = __expf(mrun - mn);
        mrun = mn;
        float rs = 0.f;
        #pragma unroll
        for (int r = 0; r < 16; ++r) {
            float p0 = __expf(s0[r] - mn);
            float p1 = __expf(s1[r] - mn);
            s0[r] = p0; s1[r] = p1;
            rs += p0 + p1;
        }
        rs += __shfl_xor(rs, 32);
        lrun = lrun * alpha + rs;
        #pragma unroll
        for (int r = 0; r < 16; ++r) { O0[r] *= alpha; O1[r] *= alpha; }

        // P^T -> LDS as [q][key]
        #pragma unroll
        for (int r = 0; r < 16; ++r) {
            int krel = (r & 3) + ((r >> 2) << 3) + 4 * laneK;
            Pl[laneM * 68 + krel]      = s0[r];
            Pl[laneM * 68 + 32 + krel] = s1[r];
        }
        __asm__ volatile("s_waitcnt lgkmcnt(0)" ::: "memory");
        __builtin_amdgcn_sched_barrier(0);

        // O^T += Vt P^T
        #pragma unroll
        for (int ks = 0; ks < 4; ++ks) {
            const float* pr = &Pl[laneM * 68 + 16 * ks + 8 * laneK];
            float4 pa = *(const float4*)pr;
            float4 pb = *(const float4*)(pr + 4);
            float pv[8] = {pa.x, pa.y, pa.z, pa.w, pb.x, pb.y, pb.z, pb.w};
            bhalf8 ph, plo;                     // RTZ split (P >= 0)
            #pragma unroll
            for (int i = 0; i < 8; ++i) {
                unsigned u = __float_as_uint(pv[i]);
                ph[i] = (short)(u >> 16);
                float lf = pv[i] - __uint_as_float(u & 0xFFFF0000u);
                plo[i] = (short)(__float_as_uint(lf) >> 16);
            }
            int db = 32 * ks + 16 * laneK;
            {
                int col = laneM;
                int o = (col * 128 + db) ^ ((col & 7) << 4);
                bhalf8 vh = *(const bhalf8*)(lds + 16384 + o);
                bhalf8 vl = *(const bhalf8*)(lds + 24576 + o);
                O0 = __builtin_amdgcn_mfma_f32_32x32x16_bf16(vh, ph,  O0, 0, 0, 0);
                O0 = __builtin_amdgcn_mfma_f32_32x32x16_bf16(vl, ph,  O0, 0, 0, 0);
                O0 = __builtin_amdgcn_mfma_f32_32x32x16_bf16(vh, plo, O0, 0, 0, 0);
            }
            {
                int col = 32 + laneM;
                int o = (col * 128 + db) ^ ((col & 7) << 4);
                bhalf8 vh = *(const bhalf8*)(lds + 16384 + o);
                bhalf8 vl = *(const bhalf8*)(lds + 24576 + o);
                O1 = __builtin_amdgcn_mfma_f32_32x32x16_bf16(vh, ph,  O1, 0, 0, 0);
                O1 = __builtin_amdgcn_mfma_f32_32x32x16_bf16(vl, ph,  O1, 0, 0, 0);
                O1 = __builtin_amdgcn_mfma_f32_32x32x16_bf16(vh, plo, O1, 0, 0, 0);
            }
        }
    }

    // Epilogue: transpose O^T through per-wave LDS, coalesced bf16-pair store
    float inv = 1.0f / lrun;
    #pragma unroll
    for (int r = 0; r < 16; ++r) {
        int d = (r & 3) + ((r >> 2) << 3) + 4 * laneK;
        Pl[laneM * 68 + d]      = O0[r] * inv;
        Pl[laneM * 68 + 32 + d] = O1[r] * inv;
    }
    __asm__ volatile("s_waitcnt lgkmcnt(0)" ::: "memory");
    __builtin_amdgcn_sched_barrier(0);
    #pragma unroll
    for (int it = 0; it < 16; ++it) {
        int qr = it * 2 + (lane >> 5);          // q-row within wave band
        int d  = (lane & 31) * 2;
        float2 v = *(const float2*)&Pl[qr * 68 + d];
        unsigned short h0, l0, h1, l1;
        split_bf16(v.x, h0, l0);
        split_bf16(v.y, h1, l1);
        size_t base = (size_t)(b * SS + q0 + 32 * wq + qr) * 512 + hh * 64 + d;
        ushort2 hv; hv.x = h0; hv.y = h1;
        ushort2 lv; lv.x = l0; lv.y = l1;
        *(ushort2*)(avh + base) = hv;
        *(ushort2*)(avl + base) = lv;
    }
}

// ---------------------------------------------------------------------------
// Fused residual-add + LayerNorm; also emits bf16 hi/lo pair of the output.
// ---------------------------------------------------------------------------
__global__ __launch_bounds__(256) void add_ln_kernel(
    float* __restrict__ h, const float* __restrict__ x,
    const float* __restrict__ g, const float* __restrict__ bta,
    unsigned short* __restrict__ hhi, unsigned short* __restrict__ hlo)
{
    int tok = blockIdx.x, tid = threadIdx.x;
    size_t base = (size_t)tok * DD;
    float v0 = h[base + tid] + x[base + tid];
    float v1 = h[base + 256 + tid] + x[base + 256 + tid];

    __shared__ float rs[256], rq[256];
    rs[tid] = v0 + v1;
    rq[tid] = v0 * v0 + v1 * v1;
    __syncthreads();
    for (int off = 128; off > 0; off >>= 1) {
        if (tid < off) { rs[tid] += rs[tid + off]; rq[tid] += rq[tid + off]; }
        __syncthreads();
    }
    float mean = rs[0] * (1.f / 512.f);
    float var  = rq[0] * (1.f / 512.f) - mean * mean;
    float inv  = rsqrtf(var + 1e-5f);
    float o0 = (v0 - mean) * inv * g[tid]       + bta[tid];
    float o1 = (v1 - mean) * inv * g[256 + tid] + bta[256 + tid];
    h[base + tid]       = o0;
    h[base + 256 + tid] = o1;
    unsigned short a, b;
    split_bf16(o0, a, b); hhi[base + tid]       = a; hlo[base + tid]       = b;
    split_bf16(o1, a, b); hhi[base + 256 + tid] = a; hlo[base + 256 + tid] = b;
}

// ---------------------------------------------------------------------------
extern "C" void kernel_launch(void* const* d_in, const int* in_sizes, int n_in,
                              void* d_out, int out_size, void* d_ws, size_t ws_size,
                              hipStream_t stream)
{
    const int*   data = (const int*)d_in[0];
    const float* we   = (const float*)d_in[1];   // word_emb [V, D]
    const float* pe   = (const float*)d_in[2];   // pos_emb
    const float* Wq   = (const float*)d_in[3];   // [L, 512, 512]
    const float* Wkv  = (const float*)d_in[4];   // [L, 1024, 512]
    const float* Wo   = (const float*)d_in[5];   // [L, 512, 512]
    const float* g1   = (const float*)d_in[6];
    const float* bl1  = (const float*)d_in[7];
    const float* W1   = (const float*)d_in[8];   // [L, 2048, 512]
    const float* b1   = (const float*)d_in[9];
    const float* W2   = (const float*)d_in[10];  // [L, 512, 2048]
    const float* b2   = (const float*)d_in[11];
    const float* g2   = (const float*)d_in[12];
    const float* bl2  = (const float*)d_in[13];
    const float* outb = (const float*)d_in[14];  // [V]
    float* out = (float*)d_out;

    typedef unsigned short us;
    // Workspace layout (~227 MB)
    float* h    = (float*)d_ws;                          // TT*512 f32
    us* qhp  = (us*)(h + (size_t)TT * 512);              // 8 x (TT*512 us) block
    us* qlp  = qhp  + (size_t)TT * 512;
    us* khp  = qlp  + (size_t)TT * 512;
    us* klp  = khp  + (size_t)TT * 512;
    us* vthp = klp  + (size_t)TT * 512;
    us* vtlp = vthp + (size_t)TT * 512;
    us* avh  = vtlp + (size_t)TT * 512;
    us* avl  = avh  + (size_t)TT * 512;
    float* tmp = (float*)(avl + (size_t)TT * 512);       // TT*512 f32
    us* hhi  = (us*)(tmp + (size_t)TT * 512);
    us* hlo  = hhi + (size_t)TT * 512;
    // ff pair aliases the q..av block (dead when ff is live): 2 x TT*2048 us
    us* ffh = qhp;
    us* ffl = qhp + (size_t)TT * 2048;
    // pre-converted weights (bf16 hi/lo)
    us* wqh  = hlo + (size_t)TT * 512;
    us* wql  = wqh  + (size_t)LL * 512 * 512;
    us* wkvh = wql  + (size_t)LL * 512 * 512;
    us* wkvl = wkvh + (size_t)LL * 1024 * 512;
    us* woh  = wkvl + (size_t)LL * 1024 * 512;
    us* wol  = woh  + (size_t)LL * 512 * 512;
    us* w1h  = wol  + (size_t)LL * 512 * 512;
    us* w1l  = w1h  + (size_t)LL * 2048 * 512;
    us* w2h  = w1l  + (size_t)LL * 2048 * 512;
    us* w2l  = w2h  + (size_t)LL * 512 * 2048;
    us* weh  = w2l  + (size_t)LL * 512 * 2048;
    us* wel  = weh  + (size_t)VV * 512;

    auto cv = [&](const float* s, us* hh, us* ll, size_t n) {
        int n4 = (int)(n >> 2);
        int blocks = (n4 + 255) / 256;
        if (blocks > 2048) blocks = 2048;
        convsplit<<<blocks, 256, 0, stream>>>(s, hh, ll, n4);
    };
    cv(Wq,  wqh,  wql,  (size_t)LL * 512 * 512);
    cv(Wkv, wkvh, wkvl, (size_t)LL * 1024 * 512);
    cv(Wo,  woh,  wol,  (size_t)LL * 512 * 512);
    cv(W1,  w1h,  w1l,  (size_t)LL * 2048 * 512);
    cv(W2,  w2h,  w2l,  (size_t)LL * 512 * 2048);
    cv(we,  weh,  wel,  (size_t)VV * 512);

    embed_kernel<<<TT, 256, 0, stream>>>(data, we, pe, h, hhi, hlo);

    for (int l = 0; l < LL; ++l) {
        const us* lwqh  = wqh  + (size_t)l * 512 * 512;
        const us* lwql  = wql  + (size_t)l * 512 * 512;
        const us* lwkvh = wkvh + (size_t)l * 1024 * 512;
        const us* lwkvl = wkvl + (size_t)l * 1024 * 512;
        const us* lwoh  = woh  + (size_t)l * 512 * 512;
        const us* lwol  = wol  + (size_t)l * 512 * 512;
        const us* lw1h  = w1h  + (size_t)l * 2048 * 512;
        const us* lw1l  = w1l  + (size_t)l * 2048 * 512;
        const us* lw2h  = w2h  + (size_t)l * 512 * 2048;
        const us* lw2l  = w2l  + (size_t)l * 512 * 2048;

        gemm_mfma<64, 3, false><<<dim3(8, 32), 256, 0, stream>>>(
            hhi, hlo, lwqh, lwql, nullptr, nullptr, qhp, qlp, nullptr, nullptr, 512, 512);
        gemm_mfma<128, 4, false><<<dim3(8, 32), 256, 0, stream>>>(
            hhi, hlo, lwkvh, lwkvl, nullptr, nullptr, khp, klp, vthp, vtlp, 1024, 512);
        flash_mfma<<<dim3(16, HH, BB), 128, 0, stream>>>(
            qhp, qlp, khp, klp, vthp, vtlp, avh, avl);
        gemm_mfma<64, 0, false><<<dim3(8, 32), 256, 0, stream>>>(
            avh, avl, lwoh, lwol, nullptr, tmp, nullptr, nullptr, nullptr, nullptr, 512, 512);
        add_ln_kernel<<<TT, 256, 0, stream>>>(h, tmp, g1 + l * 512, bl1 + l * 512, hhi, hlo);
        gemm_mfma<128, 2, false><<<dim3(16, 32), 256, 0, stream>>>(
            hhi, hlo, lw1h, lw1l, b1 + l * 2048, nullptr, ffh, ffl, nullptr, nullptr, 2048, 512);
        gemm_mfma<64, 1, false><<<dim3(8, 32), 256, 0, stream>>>(
            ffh, ffl, lw2h, lw2l, b2 + l * 512, tmp, nullptr, nullptr, nullptr, nullptr, 512, 2048);
        add_ln_kernel<<<TT, 256, 0, stream>>>(h, tmp, g2 + l * 512, bl2 + l * 512, hhi, hlo);
    }

    // logits = h @ word_emb^T + out_b (tied), N = 10000, XCD-swizzled grid
    gemm_mfma<128, 1, true><<<dim3((VV + 127) / 128, 32), 256, 0, stream>>>(
        hhi, hlo, weh, wel, outb, out, nullptr, nullptr, nullptr, nullptr, VV, 512);
}